// Round 6
// baseline (140.530 us; speedup 1.0000x reference)
//
#include <hip/hip_runtime.h>
#include <math.h>

#define Bn   64
#define Nn   512
#define Dn   256
#define IMGn 51

typedef __attribute__((ext_vector_type(8))) short bf16x8;
typedef __attribute__((ext_vector_type(4))) float f32x4;
typedef __attribute__((ext_vector_type(4))) unsigned short u16x4;

__device__ inline unsigned short f2b(float f) {            // fp32 -> bf16 RNE
    union { float f; unsigned u; } v; v.f = f;
    unsigned r = v.u + 0x7fffu + ((v.u >> 16) & 1u);
    return (unsigned short)(r >> 16);
}

// ---- fused prep: l2norm(input_2)->T, cvt(input_1)->A0, cvt weights ------------
__global__ __launch_bounds__(256) void k_prep(const float* __restrict__ in1,
                                              const float* __restrict__ in2,
                                              const float* __restrict__ w0,
                                              const float* __restrict__ w1,
                                              const float* __restrict__ wf,
                                              unsigned short* __restrict__ A0,
                                              unsigned short* __restrict__ T,
                                              unsigned short* __restrict__ w0b,
                                              unsigned short* __restrict__ w1b,
                                              unsigned short* __restrict__ wfb) {
    const int bid = blockIdx.x, tid = threadIdx.x;
    if (bid < 8192) {                                      // norm: 4 rows/block
        const int row = bid * 4 + (tid >> 6);
        const int lane = tid & 63;
        float4 v = ((const float4*)(in2 + (size_t)row * Dn))[lane];
        float ss = v.x * v.x + v.y * v.y + v.z * v.z + v.w * v.w;
#pragma unroll
        for (int m = 1; m < 64; m <<= 1) ss += __shfl_xor(ss, m);
        float inv = 1.0f / fmaxf(sqrtf(ss), 1e-8f);
        u16x4 o = { f2b(v.x*inv), f2b(v.y*inv), f2b(v.z*inv), f2b(v.w*inv) };
        ((u16x4*)(T + (size_t)row * Dn))[lane] = o;
    } else if (bid < 10240) {                              // cvt input_1
        int i = (bid - 8192) * 256 + tid;
#pragma unroll
        for (int q = 0; q < 4; ++q, i += 524288) {
            float4 v = ((const float4*)in1)[i];
            u16x4 o = { f2b(v.x), f2b(v.y), f2b(v.z), f2b(v.w) };
            ((u16x4*)A0)[i] = o;
        }
    } else {                                               // cvt weights
        const int b2 = bid - 10240;
        const float* src = (b2 < 64) ? w0 : (b2 < 128) ? w1 : wf;
        unsigned short* dst = (b2 < 64) ? w0b : (b2 < 128) ? w1b : wfb;
        const int i = (b2 & 63) * 256 + tid;
        float4 v = ((const float4*)src)[i];
        u16x4 o = { f2b(v.x), f2b(v.y), f2b(v.z), f2b(v.w) };
        ((u16x4*)dst)[i] = o;
    }
}

// ---------------- MFMA GEMM core: C = A(128xK) * Bt(128xK)^T -------------------
// Tile 128x128, BK=32, 4 waves (2x2), 4x4 frags of 16x16x32 per wave.
// NBUF=2: wait vmcnt(0) on loads issued one full compute-phase earlier, then
//   barrier, then issue t+1 (34KB LDS -> 4 blocks/CU).
// NBUF=3: depth-2 counted vmcnt(4) (48KB LDS), loads get 2 phases of cover.
// Source-side XOR swizzle keeps frag ds_read_b128 at free 2-way aliasing.

__device__ inline void stage128x32(const unsigned short* __restrict__ src, int ldk,
                                   char* ldsbase, int tid) {
    const int wave = tid >> 6, lane = tid & 63;
#pragma unroll
    for (int it = 0; it < 2; ++it) {
        const int chunk = wave * 128 + it * 64 + lane;   // 512 chunks of 16B
        const int row = chunk >> 2, s = chunk & 3;
        const char* g = (const char*)(src + (size_t)row * ldk) + ((s ^ ((row >> 1) & 3)) << 4);
        char* l = ldsbase + (size_t)(wave * 2048 + it * 1024);   // wave-uniform base
        __builtin_amdgcn_global_load_lds((const __attribute__((address_space(1))) void*)g,
                                         (__attribute__((address_space(3))) void*)l,
                                         16, 0, 0);
    }
}

__device__ inline bf16x8 frag(const char* ldsbase, int row, int s) {
    return *(const bf16x8*)(ldsbase + row * 64 + ((s ^ ((row >> 1) & 3)) << 4));
}

enum { EPI_GRAM = 0, EPI_TRANS = 1, EPI_BIASH = 2, EPI_FINAL = 3 };

template<int EPI, int NBUF>
__global__ __launch_bounds__(256) void k_mfma(const unsigned short* __restrict__ Abase,
                                              const unsigned short* __restrict__ Bbase,
                                              void* __restrict__ outp,
                                              const float* __restrict__ bias,
                                              const int* __restrict__ noun,
                                              int K, int lda, int ldb, long sA, long sB) {
    extern __shared__ char smem[];
    const int tid = threadIdx.x, lane = tid & 63, wave = tid >> 6;
    const int wr = wave >> 1, wc = wave & 1;
    const int r16 = lane & 15, s = lane >> 4;
    (void)lane;

    // bijective XCD swizzle (all our grids have nwg % 8 == 0)
    const int nwg = gridDim.x * gridDim.y * gridDim.z;
    const int wg  = blockIdx.x + gridDim.x * (blockIdx.y + gridDim.y * blockIdx.z);
    const int swz = (wg & 7) * (nwg >> 3) + (wg >> 3);
    const int tile_x = swz % gridDim.x;
    const int rem    = swz / gridDim.x;
    const int tile_y = rem % gridDim.y;
    const size_t bz  = rem / gridDim.y;

    const unsigned short* A  = Abase + bz * sA + (size_t)tile_y * 128 * lda;
    const unsigned short* Bt = Bbase + bz * sB + (size_t)tile_x * 128 * ldb;

    f32x4 acc[4][4];
#pragma unroll
    for (int m = 0; m < 4; ++m)
#pragma unroll
        for (int n = 0; n < 4; ++n)
            acc[m][n] = (f32x4){0.f, 0.f, 0.f, 0.f};

    const int NT = K >> 5;

    if constexpr (NBUF == 2) {
        stage128x32(A,  lda, smem,        tid);
        stage128x32(Bt, ldb, smem + 8192, tid);
        for (int t = 0; t < NT; ++t) {
            asm volatile("s_waitcnt vmcnt(0)" ::: "memory");   // tile t (issued last iter)
            __builtin_amdgcn_s_barrier();
            __builtin_amdgcn_sched_barrier(0);
            if (t + 1 < NT) {                                  // issue tile t+1
                char* nb = smem + 16384 * ((t + 1) & 1);
                stage128x32(A  + (t + 1) * 32, lda, nb,        tid);
                stage128x32(Bt + (t + 1) * 32, ldb, nb + 8192, tid);
            }
            __builtin_amdgcn_sched_barrier(0);
            const char* cb = smem + 16384 * (t & 1);
            bf16x8 af[4], bv[4];
#pragma unroll
            for (int m = 0; m < 4; ++m) af[m] = frag(cb, wr * 64 + m * 16 + r16, s);
#pragma unroll
            for (int n = 0; n < 4; ++n) bv[n] = frag(cb + 8192, wc * 64 + n * 16 + r16, s);
#pragma unroll
            for (int m = 0; m < 4; ++m)
#pragma unroll
                for (int n = 0; n < 4; ++n)
                    acc[m][n] = __builtin_amdgcn_mfma_f32_16x16x32_bf16(af[m], bv[n], acc[m][n], 0, 0, 0);
        }
    } else {
        // 3-buffer depth-2, counted vmcnt (never 0 in-loop)
        stage128x32(A,       lda, smem,                tid);
        stage128x32(Bt,      ldb, smem + 8192,         tid);
        stage128x32(A + 32,  lda, smem + 16384,        tid);
        stage128x32(Bt + 32, ldb, smem + 16384 + 8192, tid);
        for (int t = 0; t < NT; ++t) {
            if (t < NT - 1) { asm volatile("s_waitcnt vmcnt(4)" ::: "memory"); }
            else            { asm volatile("s_waitcnt vmcnt(0)" ::: "memory"); }
            __builtin_amdgcn_s_barrier();
            __builtin_amdgcn_sched_barrier(0);
            if (t + 2 < NT) {                                  // issue tile t+2
                char* nb = smem + 16384 * ((t + 2) % 3);
                stage128x32(A  + (t + 2) * 32, lda, nb,        tid);
                stage128x32(Bt + (t + 2) * 32, ldb, nb + 8192, tid);
            }
            __builtin_amdgcn_sched_barrier(0);
            const char* cb = smem + 16384 * (t % 3);
            bf16x8 af[4], bv[4];
#pragma unroll
            for (int m = 0; m < 4; ++m) af[m] = frag(cb, wr * 64 + m * 16 + r16, s);
#pragma unroll
            for (int n = 0; n < 4; ++n) bv[n] = frag(cb + 8192, wc * 64 + n * 16 + r16, s);
#pragma unroll
            for (int m = 0; m < 4; ++m)
#pragma unroll
                for (int n = 0; n < 4; ++n)
                    acc[m][n] = __builtin_amdgcn_mfma_f32_16x16x32_bf16(af[m], bv[n], acc[m][n], 0, 0, 0);
        }
    }
    __syncthreads();       // before reusing smem as epilogue bounce

    const int row0 = tile_y * 128, col0 = tile_x * 128;
    unsigned short* lt = (unsigned short*)smem;            // [128][136] bf16 bounce
    const int row = tid >> 1, h = tid & 1;

    if constexpr (EPI == EPI_GRAM) {
        const int* nm = noun + bz * Nn;
        unsigned short* out = (unsigned short*)outp + bz * ((size_t)Nn * Nn);
#pragma unroll
        for (int n = 0; n < 4; ++n) {
            const int cl = wc * 64 + n * 16 + r16;
            const int c  = col0 + cl;
            const float nmc = (c < IMGn) ? 0.f : (float)nm[c];
#pragma unroll
            for (int m = 0; m < 4; ++m)
#pragma unroll
                for (int i = 0; i < 4; ++i) {
                    const int rl = wr * 64 + m * 16 + s * 4 + i;
                    const int r  = row0 + rl;
                    float mask;
                    if (r < IMGn)      mask = nmc;
                    else if (c < IMGn) mask = (float)nm[r];
                    else               mask = 1.f;
                    lt[rl * 136 + cl] = f2b(acc[m][n][i] * mask);
                }
        }
        __syncthreads();
        const bf16x8* srcv = (const bf16x8*)(lt + (size_t)row * 136 + h * 64);
        bf16x8* dstv = (bf16x8*)(out + (size_t)(row0 + row) * Nn + col0 + h * 64);
#pragma unroll
        for (int q = 0; q < 8; ++q) dstv[q] = srcv[q];
    } else if constexpr (EPI == EPI_BIASH) {
#pragma unroll
        for (int n = 0; n < 4; ++n) {
            const int cl = wc * 64 + n * 16 + r16;
            const float bvv = bias[col0 + cl];
#pragma unroll
            for (int m = 0; m < 4; ++m)
#pragma unroll
                for (int i = 0; i < 4; ++i) {
                    const int rl = wr * 64 + m * 16 + s * 4 + i;
                    lt[rl * 136 + cl] = f2b(fmaxf(acc[m][n][i] + bvv, 0.f));
                }
        }
        __syncthreads();
        unsigned short* out = (unsigned short*)outp + bz * ((size_t)Nn * Dn);
        const bf16x8* srcv = (const bf16x8*)(lt + (size_t)row * 136 + h * 64);
        bf16x8* dstv = (bf16x8*)(out + (size_t)(row0 + row) * Dn + col0 + h * 64);
#pragma unroll
        for (int q = 0; q < 8; ++q) dstv[q] = srcv[q];
    } else if constexpr (EPI == EPI_FINAL) {
        // fp32 out via LDS bounce, two 64-col passes; lt32 is [128][68] f32
        float* lt32 = (float*)smem;
        float* out = (float*)outp;
#pragma unroll
        for (int p = 0; p < 2; ++p) {
            if (p) __syncthreads();
            if (wc == p) {
#pragma unroll
                for (int n = 0; n < 4; ++n) {
                    const int cll = n * 16 + r16;
                    const float bvv = bias[col0 + p * 64 + cll];
#pragma unroll
                    for (int m = 0; m < 4; ++m)
#pragma unroll
                        for (int i = 0; i < 4; ++i) {
                            const int rl = wr * 64 + m * 16 + s * 4 + i;
                            lt32[rl * 68 + cll] = fmaxf(acc[m][n][i] + bvv, 0.f);
                        }
                }
            }
            __syncthreads();
            const float4* srcv = (const float4*)(lt32 + (size_t)row * 68 + h * 32);
            float4* dstv = (float4*)(out + (size_t)(row0 + row) * Dn + col0 + p * 64 + h * 32);
#pragma unroll
            for (int q = 0; q < 8; ++q) dstv[q] = srcv[q];
        }
    } else {  // EPI_TRANS: out Ut[b][c][r_local], via padded-LDS transpose bounce
#pragma unroll
        for (int n = 0; n < 4; ++n)
#pragma unroll
            for (int m = 0; m < 4; ++m)
#pragma unroll
                for (int i = 0; i < 4; ++i) {
                    const int ct = wc * 64 + n * 16 + r16;
                    const int rt = wr * 64 + m * 16 + s * 4 + i;
                    lt[ct * 136 + rt] = f2b(acc[m][n][i]);
                }
        __syncthreads();
        const int bm = tile_y;
        const size_t bb = bm >> 2;
        const int rl0 = (bm & 3) * 128;
        unsigned short* out = (unsigned short*)outp + bb * ((size_t)Dn * Nn);
        const int ct = tid >> 1;
        const bf16x8* srcv = (const bf16x8*)(lt + (size_t)ct * 136 + h * 64);
        bf16x8* dstv = (bf16x8*)(out + (size_t)(col0 + ct) * Nn + rl0 + h * 64);
#pragma unroll
        for (int q = 0; q < 8; ++q) dstv[q] = srcv[q];
    }
}

extern "C" void kernel_launch(void* const* d_in, const int* in_sizes, int n_in,
                              void* d_out, int out_size, void* d_ws, size_t ws_size,
                              hipStream_t stream) {
    const float* input_1 = (const float*)d_in[0];
    const float* input_2 = (const float*)d_in[1];
    const int*   noun    = (const int*)d_in[3];
    const float* w0 = (const float*)d_in[4];
    const float* b0 = (const float*)d_in[5];
    const float* w1 = (const float*)d_in[6];
    const float* b1 = (const float*)d_in[7];
    const float* wf = (const float*)d_in[8];
    const float* bf = (const float*)d_in[9];

    unsigned short* ws  = (unsigned short*)d_ws;
    unsigned short* T   = ws;                    // 64*512*256
    unsigned short* A0  = ws + 8388608;          // input_1 bf16
    unsigned short* adj = ws + 16777216;         // 64*512*512
    unsigned short* Ut  = ws + 33554432;         // 64*256*512
    unsigned short* H1  = ws + 41943040;
    unsigned short* H2  = ws + 50331648;
    unsigned short* w0b = ws + 58720256;
    unsigned short* w1b = w0b + 65536;
    unsigned short* wfb = w1b + 65536;

    dim3 blk(256);
    k_prep<<<10432, blk, 0, stream>>>(input_1, input_2, w0, w1, wf, A0, T, w0b, w1b, wfb);

    // adj = mask .* (T T^T)                      full 16 tiles, 1024 blocks
    k_mfma<EPI_GRAM, 2><<<dim3(4, 4, Bn), blk, 34816, stream>>>(
        T, T, adj, nullptr, noun, 256, 256, 256, (long)Nn * Dn, (long)Nn * Dn);
    // Ut0 = (input_1 @ w0^T)^T                   M=32768 flat, N=256, K=256
    k_mfma<EPI_TRANS, 3><<<dim3(2, 256, 1), blk, 49152, stream>>>(
        A0, w0b, Ut, nullptr, nullptr, 256, 256, 256, 0, 0);
    // H1 = relu(adj @ Ut0^T + b0)                M=512/batch, N=256, K=512
    k_mfma<EPI_BIASH, 3><<<dim3(2, 4, Bn), blk, 49152, stream>>>(
        adj, Ut, H1, b0, nullptr, 512, 512, 512, (long)Nn * Nn, (long)Dn * Nn);
    // Ut1 = (H1 @ w1^T)^T
    k_mfma<EPI_TRANS, 3><<<dim3(2, 256, 1), blk, 49152, stream>>>(
        H1, w1b, Ut, nullptr, nullptr, 256, 256, 256, 0, 0);
    // H2 = relu(adj @ Ut1^T + b1)
    k_mfma<EPI_BIASH, 3><<<dim3(2, 4, Bn), blk, 49152, stream>>>(
        adj, Ut, H2, b1, nullptr, 512, 512, 512, (long)Nn * Nn, (long)Dn * Nn);
    // out = relu(H2 @ wf^T + bf)  (fp32 out)
    k_mfma<EPI_FINAL, 3><<<dim3(2, 256, 1), blk, 49152, stream>>>(
        H2, wfb, d_out, bf, nullptr, 256, 256, 256, 0, 0);
}